// Round 9
// baseline (151.414 us; speedup 1.0000x reference)
//
#include <hip/hip_runtime.h>
#include <math.h>

#define EPSN 1e-4f
#define SEQ 2304

using bf16x8 = __attribute__((ext_vector_type(8))) short;
using f32x4  = __attribute__((ext_vector_type(4))) float;

__device__ inline unsigned short f2bf(float x) {
    union { float f; unsigned u; } c; c.f = x;
    unsigned u = c.u;
    u += 0x7fffu + ((u >> 16) & 1u);
    return (unsigned short)(u >> 16);
}

// HW packed f32->bf16 (RNE), gfx950.
__device__ inline unsigned cvt_pk_bf16(float lo, float hi) {
    unsigned r;
    asm("v_cvt_pk_bf16_f32 %0, %1, %2" : "=v"(r) : "v"(lo), "v"(hi));
    return r;
}
// gfx950 cross-row swaps (verified passing R3-R8).
__device__ inline void permlane32_swap(unsigned &a, unsigned &b) {
    asm("v_permlane32_swap_b32 %0, %1" : "+v"(a), "+v"(b));
}
__device__ inline void permlane16_swap(unsigned &a, unsigned &b) {
    asm("v_permlane16_swap_b32 %0, %1" : "+v"(a), "+v"(b));
}

// ---------------- Kernel 1: weight-norm only (256 blocks) ----------------
__global__ __launch_bounds__(256) void prep_w_kernel(const float* __restrict__ w_qkv,
                                                     const float* __restrict__ w_out,
                                                     unsigned short* __restrict__ wqb,
                                                     unsigned short* __restrict__ wob) {
    int wave = threadIdx.x >> 6, lane = threadIdx.x & 63;
    int row = blockIdx.x * 4 + wave;
    const float* src;
    unsigned short* dst;
    if (row < 768) { src = w_qkv + (size_t)row * 256; dst = wqb + (size_t)row * 256; }
    else           { src = w_out + (size_t)(row - 768) * 256; dst = wob + (size_t)(row - 768) * 256; }
    float4 v = *(const float4*)&src[lane * 4];
    float ss = v.x * v.x + v.y * v.y + v.z * v.z + v.w * v.w;
    for (int off = 32; off > 0; off >>= 1) ss += __shfl_xor(ss, off, 64);
    float sc = 1.0f / (sqrtf(ss) + 16.0f * EPSN);
    unsigned p0 = (unsigned)f2bf(v.x * sc) | ((unsigned)f2bf(v.y * sc) << 16);
    unsigned p1 = (unsigned)f2bf(v.z * sc) | ((unsigned)f2bf(v.w * sc) << 16);
    *(uint2*)&dst[lane * 4] = make_uint2(p0, p1);
}

// ---------------- Kernel 2: fused x-transpose + QKV GEMM + d-normalize (1152 blocks) ----------------
// UNCHANGED from R8 (verified passing).
__global__ __launch_bounds__(256) void qkv_fused_kernel(const float* __restrict__ x,
                                                        const unsigned short* __restrict__ wqb,
                                                        unsigned short* __restrict__ qn,
                                                        unsigned short* __restrict__ kn,
                                                        unsigned short* __restrict__ vn) {
    __shared__ __align__(16) unsigned short Xs[32][264];
    __shared__ float Cs[96][33];
    __shared__ __align__(16) unsigned short Vls[32][40];
    int bid = blockIdx.x;                   // 0..1151
    int xcd = bid & 7, j = bid >> 3;        // j 0..143
    int h = j & 7;
    int tile = xcd * 18 + (j >> 3);         // 0..143
    int st2 = tile % 72, n = tile / 72;     // 32-s tile, batch
    int tid = threadIdx.x;
    int wave = tid >> 6, lane = tid & 63;
    int ln = lane & 15, quad = lane >> 4;
    int sgrp = wave & 1, mgrp = wave >> 1;
    int s0 = st2 * 32;

    // stage x[n][c][s0..s0+31] -> Xs[s][c] bf16
    {
        int ci = tid >> 3, sv = (tid & 7) * 4;
#pragma unroll
        for (int p = 0; p < 8; ++p) {
            int c = p * 32 + ci;
            float4 v = *(const float4*)&x[(size_t)(n * 256 + c) * SEQ + s0 + sv];
            Xs[sv + 0][c] = f2bf(v.x);
            Xs[sv + 1][c] = f2bf(v.y);
            Xs[sv + 2][c] = f2bf(v.z);
            Xs[sv + 3][c] = f2bf(v.w);
        }
    }
    __syncthreads();

    const unsigned short* Abase = wqb + (size_t)(h * 96 + mgrp * 48 + ln) * 256 + quad * 8;
    f32x4 acc[3];
#pragma unroll
    for (int m = 0; m < 3; ++m) acc[m] = (f32x4){0.f, 0.f, 0.f, 0.f};
#pragma unroll
    for (int kc = 0; kc < 8; ++kc) {
        bf16x8 b = *(const bf16x8*)&Xs[sgrp * 16 + ln][kc * 32 + quad * 8];
#pragma unroll
        for (int m = 0; m < 3; ++m) {
            bf16x8 a = *(const bf16x8*)(Abase + (size_t)(m * 16) * 256 + kc * 32);
            acc[m] = __builtin_amdgcn_mfma_f32_16x16x32_bf16(a, b, acc[m], 0, 0, 0);
        }
    }
#pragma unroll
    for (int m = 0; m < 3; ++m)
#pragma unroll
        for (int r = 0; r < 4; ++r)
            Cs[mgrp * 48 + m * 16 + quad * 4 + r][sgrp * 16 + ln] = acc[m][r];
    __syncthreads();
    int nh = n * 8 + h;
    if (tid < 96) {
        int sl = tid & 31, wh = tid >> 5;
        int s = st2 * 32 + sl;
        float v[32];
        float ss = 0.f;
#pragma unroll
        for (int d = 0; d < 32; ++d) { v[d] = Cs[3 * d + wh][sl]; ss += v[d] * v[d]; }
        float inv = 1.0f / (EPSN + sqrtf(ss * (1.0f / 32.0f)));
        // fold softmax scale (1/sqrt(32)) AND log2(e) into q so attn uses exp2
        if (wh == 0) inv *= 0.17677669529663687f * 1.4426950408889634f;
        if (wh == 2) {
#pragma unroll
            for (int d = 0; d < 32; ++d) Vls[d][sl] = f2bf(v[d] * inv);
        } else {
            unsigned short* dst = (wh == 1 ? kn : qn) + (size_t)nh * 73728 + (size_t)s * 32;
            unsigned wbuf[16];
#pragma unroll
            for (int j2 = 0; j2 < 16; ++j2)
                wbuf[j2] = (unsigned)f2bf(v[2 * j2] * inv) | ((unsigned)f2bf(v[2 * j2 + 1] * inv) << 16);
#pragma unroll
            for (int j2 = 0; j2 < 4; ++j2) {
                uint4 t4 = make_uint4(wbuf[4 * j2], wbuf[4 * j2 + 1], wbuf[4 * j2 + 2], wbuf[4 * j2 + 3]);
                *(uint4*)(dst + j2 * 8) = t4;
            }
        }
    }
    __syncthreads();
    {
        int d = tid >> 3, sj = (tid & 7) * 4;
        uint2 t2 = *(const uint2*)&Vls[d][sj];
        *(uint2*)&vn[(size_t)nh * 73728 + (size_t)d * SEQ + st2 * 32 + sj] = t2;
    }
}

// ---------------- Kernel 3: LDS-FREE MFMA flash attention, split-K=4 (2304 blocks) ----------------
// Both MFMA operands are loaded DIRECTLY from global in fragment layout:
//   QK A-frag:  kn[(sTile+c*16+ln)*32 + quad*8]  (wave covers 1KB contiguous)
//   PV  B-frag: vn[d*SEQ + sTile+kc*32+quad*8]   (64B segments per d-row)
// K/V are L2-resident (2 heads/XCD = 600KB) and L1-shared across the CU's waves.
// No LDS, no barriers: 4 waves/block fully independent.
__global__ __launch_bounds__(256) void attn_mfma_kernel(const unsigned short* __restrict__ qn,
                                                        const unsigned short* __restrict__ kn,
                                                        const unsigned short* __restrict__ vn,
                                                        float* __restrict__ Opart,
                                                        float* __restrict__ Lpart) {
    int tid = threadIdx.x;
    int wq = tid >> 6, lane = tid & 63;
    int ln = lane & 15, quad = lane >> 4;
    int bid = blockIdx.x;
    int xcd = bid & 7, bi = bid >> 3;       // bi 0..287
    int nh = xcd * 2 + (bi >= 144);
    int bi2 = (bi >= 144) ? bi - 144 : bi;  // 0..143
    int qt = bi2 % 36, kz = bi2 / 36;       // kz 0..3
    const unsigned short* Qg = qn + (size_t)nh * 73728;
    const unsigned short* Kg = kn + (size_t)nh * 73728;
    const unsigned short* Vg = vn + (size_t)nh * 73728;

    bf16x8 qf = *(const bf16x8*)(Qg + (size_t)(qt * 64 + wq * 16 + ln) * 32 + quad * 8);
    bf16x8 ones;
#pragma unroll
    for (int i = 0; i < 8; ++i) ones[i] = (short)0x3F80;

    f32x4 o0 = {0.f, 0.f, 0.f, 0.f};
    f32x4 o1 = {0.f, 0.f, 0.f, 0.f};
    f32x4 lac = {0.f, 0.f, 0.f, 0.f};

    const int NT = 9;
    int s0 = kz * NT * 64;

    // per-lane fragment base pointers
    const unsigned short* Kb = Kg + (size_t)(s0 + ln) * 32 + quad * 8;
    const unsigned short* Vb = Vg + (size_t)ln * SEQ + s0 + quad * 8;

    for (int i = 0; i < NT; ++i) {
        const f32x4 zero = {0.f, 0.f, 0.f, 0.f};
        unsigned w[4][2];
#pragma unroll
        for (int c = 0; c < 4; ++c) {
            bf16x8 kf = *(const bf16x8*)(Kb + (size_t)(i * 64 + c * 16) * 32);
            // swapped: lane holds S[q=ln][k=c*16+quad*4+r]
            f32x4 sc = __builtin_amdgcn_mfma_f32_16x16x32_bf16(kf, qf, zero, 0, 0, 0);
            w[c][0] = cvt_pk_bf16(exp2f(sc[0]), exp2f(sc[1]));
            w[c][1] = cvt_pk_bf16(exp2f(sc[2]), exp2f(sc[3]));
        }
#pragma unroll
        for (int kc = 0; kc < 2; ++kc) {
            unsigned a0 = w[2 * kc][0], b0 = w[2 * kc + 1][0];
            permlane32_swap(a0, b0);
            permlane16_swap(a0, b0);
            unsigned a1 = w[2 * kc][1], b1 = w[2 * kc + 1][1];
            permlane32_swap(a1, b1);
            permlane16_swap(a1, b1);
            union { unsigned u[4]; bf16x8 v8; } pk;
            pk.u[0] = a0; pk.u[1] = a1; pk.u[2] = b0; pk.u[3] = b1;
            bf16x8 v0 = *(const bf16x8*)(Vb + i * 64 + kc * 32);
            bf16x8 v1 = *(const bf16x8*)(Vb + (size_t)16 * SEQ + i * 64 + kc * 32);
            lac = __builtin_amdgcn_mfma_f32_16x16x32_bf16(pk.v8, ones, lac, 0, 0, 0);
            o0  = __builtin_amdgcn_mfma_f32_16x16x32_bf16(pk.v8, v0, o0, 0, 0, 0);
            o1  = __builtin_amdgcn_mfma_f32_16x16x32_bf16(pk.v8, v1, o1, 0, 0, 0);
        }
    }

    // epilogue: write f32 partials (lac[r] is the row-sum for the same q-row as o0[r]/o1[r])
    float* Ob = Opart + ((size_t)(kz * 16 + nh) * 36 + qt) * 2048;
    float* Lb = Lpart + ((size_t)(kz * 16 + nh) * 36 + qt) * 64;
#pragma unroll
    for (int r = 0; r < 4; ++r) {
        int ql = wq * 16 + quad * 4 + r;
        Ob[ql * 32 + ln]      = o0[r];
        Ob[ql * 32 + 16 + ln] = o1[r];
        if (ln == 0) Lb[ql] = lac[r];
    }
}

// ---------------- Kernel 4: fused split-K reduce + out GEMM + residual (1152 blocks) ----------------
// UNCHANGED from R8 (verified passing).
__global__ __launch_bounds__(256) void out_gemm_kernel(const float* __restrict__ Opart,
                                                       const float* __restrict__ Lpart,
                                                       const unsigned short* __restrict__ wob,
                                                       const float* __restrict__ x,
                                                       float* __restrict__ out) {
    __shared__ float Linv[8][16];
    __shared__ __align__(16) unsigned short Ys[16][264];
    int bid = blockIdx.x;                  // 0..1151
    int xcd = bid & 7, j = bid >> 3;       // 0..143
    int mt = j & 3;
    int u = j >> 2;                        // 0..35
    int n = u & 1;
    int st = xcd * 18 + (u >> 1);          // 0..143 (16-s tiles)
    int qt = st >> 2;                      // 64-q tile
    int qo = (st & 3) * 16;                // offset within it
    int tid = threadIdx.x;

    // Phase A0: l sums
    if (tid < 128) {
        int h = tid >> 4, qi = tid & 15;
        size_t base = ((size_t)((n * 8 + h) * 36) + qt) * 64 + qo + qi;
        const size_t kzs = (size_t)16 * 36 * 64;
        float l = Lpart[base] + Lpart[base + kzs] + Lpart[base + 2 * kzs] + Lpart[base + 3 * kzs];
        Linv[h][qi] = 1.0f / l;
    }
    __syncthreads();
    // Phase A1: B-tile from Opart
    {
        int qi = tid >> 4, dp = tid & 15, d0 = dp * 2;
        const size_t kzs = (size_t)16 * 36 * 2048;
#pragma unroll
        for (int h = 0; h < 8; ++h) {
            size_t ob = ((size_t)((n * 8 + h) * 36) + qt) * 2048 + (size_t)(qo + qi) * 32 + d0;
            float2 a = *(const float2*)&Opart[ob];
            float2 b = *(const float2*)&Opart[ob + kzs];
            float2 e = *(const float2*)&Opart[ob + 2 * kzs];
            float2 f = *(const float2*)&Opart[ob + 3 * kzs];
            float li = Linv[h][qi];
            float r0 = ((a.x + b.x) + (e.x + f.x)) * li;
            float r1 = ((a.y + b.y) + (e.y + f.y)) * li;
            *(unsigned*)&Ys[qi][h * 32 + d0] = cvt_pk_bf16(r0, r1);
        }
    }
    __syncthreads();

    // Phase B: GEMM + residual
    int wave = tid >> 6, lane = tid & 63;
    int ln = lane & 15, quad = lane >> 4;
    int m0 = mt * 64 + wave * 16;
    const unsigned short* Abase = wob + (size_t)(m0 + ln) * 256 + quad * 8;
    f32x4 acc = (f32x4){0.f, 0.f, 0.f, 0.f};
#pragma unroll
    for (int kc = 0; kc < 8; ++kc) {
        bf16x8 a = *(const bf16x8*)(Abase + kc * 32);
        bf16x8 b = *(const bf16x8*)&Ys[ln][kc * 32 + quad * 8];
        acc = __builtin_amdgcn_mfma_f32_16x16x32_bf16(a, b, acc, 0, 0, 0);
    }
    const float c0f = 0.7f * 1.3130643285972254f;
    const float c1f = 0.3f * 1.3130643285972254f;
#pragma unroll
    for (int r = 0; r < 4; ++r) {
        int o = m0 + quad * 4 + r;
        int s = st * 16 + ln;
        size_t idx = (size_t)(n * 256 + o) * SEQ + s;
        out[idx] = c0f * x[idx] + c1f * acc[r];
    }
}

extern "C" void kernel_launch(void* const* d_in, const int* in_sizes, int n_in,
                              void* d_out, int out_size, void* d_ws, size_t ws_size,
                              hipStream_t stream) {
    (void)in_sizes; (void)n_in; (void)out_size; (void)ws_size;
    const float* x     = (const float*)d_in[0];
    const float* w_qkv = (const float*)d_in[1];
    const float* w_out = (const float*)d_in[2];
    float* out = (float*)d_out;
    float* ws  = (float*)d_ws;
    unsigned short* wqb = (unsigned short*)(ws);             // 98304 f
    unsigned short* wob = (unsigned short*)(ws + 98304);     // 32768 f
    unsigned short* qn  = (unsigned short*)(ws + 131072);    // 589824 f each
    unsigned short* kn  = (unsigned short*)(ws + 720896);
    unsigned short* vn  = (unsigned short*)(ws + 1310720);
    float* Opart = ws + 1900544;                             // 64*36*2048 = 4718592 f
    float* Lpart = ws + 6619136;                             // 64*36*64   =  147456 f

    hipLaunchKernelGGL(prep_w_kernel, dim3(256), dim3(256), 0, stream,
                       w_qkv, w_out, wqb, wob);
    hipLaunchKernelGGL(qkv_fused_kernel, dim3(1152), dim3(256), 0, stream,
                       x, wqb, qn, kn, vn);
    hipLaunchKernelGGL(attn_mfma_kernel, dim3(2304), dim3(256), 0, stream,
                       qn, kn, vn, Opart, Lpart);
    hipLaunchKernelGGL(out_gemm_kernel, dim3(1152), dim3(256), 0, stream,
                       Opart, Lpart, wob, x, out);
}

// Round 10
// 124.442 us; speedup vs baseline: 1.2167x; 1.2167x over previous
//
#include <hip/hip_runtime.h>
#include <math.h>

#define EPSN 1e-4f
#define SEQ 2304

using bf16x8 = __attribute__((ext_vector_type(8))) short;
using f32x4  = __attribute__((ext_vector_type(4))) float;

__device__ inline unsigned short f2bf(float x) {
    union { float f; unsigned u; } c; c.f = x;
    unsigned u = c.u;
    u += 0x7fffu + ((u >> 16) & 1u);
    return (unsigned short)(u >> 16);
}

// HW packed f32->bf16 (RNE), gfx950.
__device__ inline unsigned cvt_pk_bf16(float lo, float hi) {
    unsigned r;
    asm("v_cvt_pk_bf16_f32 %0, %1, %2" : "=v"(r) : "v"(lo), "v"(hi));
    return r;
}
// gfx950 cross-row swaps (verified passing R3-R9).
__device__ inline void permlane32_swap(unsigned &a, unsigned &b) {
    asm("v_permlane32_swap_b32 %0, %1" : "+v"(a), "+v"(b));
}
__device__ inline void permlane16_swap(unsigned &a, unsigned &b) {
    asm("v_permlane16_swap_b32 %0, %1" : "+v"(a), "+v"(b));
}

// ---------------- Kernel 1: weight-norm only (256 blocks) ----------------
__global__ __launch_bounds__(256) void prep_w_kernel(const float* __restrict__ w_qkv,
                                                     const float* __restrict__ w_out,
                                                     unsigned short* __restrict__ wqb,
                                                     unsigned short* __restrict__ wob) {
    int wave = threadIdx.x >> 6, lane = threadIdx.x & 63;
    int row = blockIdx.x * 4 + wave;
    const float* src;
    unsigned short* dst;
    if (row < 768) { src = w_qkv + (size_t)row * 256; dst = wqb + (size_t)row * 256; }
    else           { src = w_out + (size_t)(row - 768) * 256; dst = wob + (size_t)(row - 768) * 256; }
    float4 v = *(const float4*)&src[lane * 4];
    float ss = v.x * v.x + v.y * v.y + v.z * v.z + v.w * v.w;
    for (int off = 32; off > 0; off >>= 1) ss += __shfl_xor(ss, off, 64);
    float sc = 1.0f / (sqrtf(ss) + 16.0f * EPSN);
    unsigned p0 = (unsigned)f2bf(v.x * sc) | ((unsigned)f2bf(v.y * sc) << 16);
    unsigned p1 = (unsigned)f2bf(v.z * sc) | ((unsigned)f2bf(v.w * sc) << 16);
    *(uint2*)&dst[lane * 4] = make_uint2(p0, p1);
}

// ---------------- Kernel 2: fused x-transpose + QKV GEMM + d-normalize (1152 blocks) ----------------
// UNCHANGED from R8 (verified passing).
__global__ __launch_bounds__(256) void qkv_fused_kernel(const float* __restrict__ x,
                                                        const unsigned short* __restrict__ wqb,
                                                        unsigned short* __restrict__ qn,
                                                        unsigned short* __restrict__ kn,
                                                        unsigned short* __restrict__ vn) {
    __shared__ __align__(16) unsigned short Xs[32][264];
    __shared__ float Cs[96][33];
    __shared__ __align__(16) unsigned short Vls[32][40];
    int bid = blockIdx.x;                   // 0..1151
    int xcd = bid & 7, j = bid >> 3;        // j 0..143
    int h = j & 7;
    int tile = xcd * 18 + (j >> 3);         // 0..143
    int st2 = tile % 72, n = tile / 72;     // 32-s tile, batch
    int tid = threadIdx.x;
    int wave = tid >> 6, lane = tid & 63;
    int ln = lane & 15, quad = lane >> 4;
    int sgrp = wave & 1, mgrp = wave >> 1;
    int s0 = st2 * 32;

    // stage x[n][c][s0..s0+31] -> Xs[s][c] bf16
    {
        int ci = tid >> 3, sv = (tid & 7) * 4;
#pragma unroll
        for (int p = 0; p < 8; ++p) {
            int c = p * 32 + ci;
            float4 v = *(const float4*)&x[(size_t)(n * 256 + c) * SEQ + s0 + sv];
            Xs[sv + 0][c] = f2bf(v.x);
            Xs[sv + 1][c] = f2bf(v.y);
            Xs[sv + 2][c] = f2bf(v.z);
            Xs[sv + 3][c] = f2bf(v.w);
        }
    }
    __syncthreads();

    const unsigned short* Abase = wqb + (size_t)(h * 96 + mgrp * 48 + ln) * 256 + quad * 8;
    f32x4 acc[3];
#pragma unroll
    for (int m = 0; m < 3; ++m) acc[m] = (f32x4){0.f, 0.f, 0.f, 0.f};
#pragma unroll
    for (int kc = 0; kc < 8; ++kc) {
        bf16x8 b = *(const bf16x8*)&Xs[sgrp * 16 + ln][kc * 32 + quad * 8];
#pragma unroll
        for (int m = 0; m < 3; ++m) {
            bf16x8 a = *(const bf16x8*)(Abase + (size_t)(m * 16) * 256 + kc * 32);
            acc[m] = __builtin_amdgcn_mfma_f32_16x16x32_bf16(a, b, acc[m], 0, 0, 0);
        }
    }
#pragma unroll
    for (int m = 0; m < 3; ++m)
#pragma unroll
        for (int r = 0; r < 4; ++r)
            Cs[mgrp * 48 + m * 16 + quad * 4 + r][sgrp * 16 + ln] = acc[m][r];
    __syncthreads();
    int nh = n * 8 + h;
    if (tid < 96) {
        int sl = tid & 31, wh = tid >> 5;
        int s = st2 * 32 + sl;
        float v[32];
        float ss = 0.f;
#pragma unroll
        for (int d = 0; d < 32; ++d) { v[d] = Cs[3 * d + wh][sl]; ss += v[d] * v[d]; }
        float inv = 1.0f / (EPSN + sqrtf(ss * (1.0f / 32.0f)));
        // fold softmax scale (1/sqrt(32)) AND log2(e) into q so attn uses exp2
        if (wh == 0) inv *= 0.17677669529663687f * 1.4426950408889634f;
        if (wh == 2) {
#pragma unroll
            for (int d = 0; d < 32; ++d) Vls[d][sl] = f2bf(v[d] * inv);
        } else {
            unsigned short* dst = (wh == 1 ? kn : qn) + (size_t)nh * 73728 + (size_t)s * 32;
            unsigned wbuf[16];
#pragma unroll
            for (int j2 = 0; j2 < 16; ++j2)
                wbuf[j2] = (unsigned)f2bf(v[2 * j2] * inv) | ((unsigned)f2bf(v[2 * j2 + 1] * inv) << 16);
#pragma unroll
            for (int j2 = 0; j2 < 4; ++j2) {
                uint4 t4 = make_uint4(wbuf[4 * j2], wbuf[4 * j2 + 1], wbuf[4 * j2 + 2], wbuf[4 * j2 + 3]);
                *(uint4*)(dst + j2 * 8) = t4;
            }
        }
    }
    __syncthreads();
    {
        int d = tid >> 3, sj = (tid & 7) * 4;
        uint2 t2 = *(const uint2*)&Vls[d][sj];
        *(uint2*)&vn[(size_t)nh * 73728 + (size_t)d * SEQ + st2 * 32 + sj] = t2;
    }
}

// ---------------- Kernel 3: MFMA flash attention, split-K=4, FRAGMENT-MAJOR LDS ----------------
// R8 structure (2-deep staging, double buffer, 1 barrier/tile) with the LDS re-laid
// out fragment-major: tile stored as frag[f][lane][16B], so every ds_read_b128 is
// addr = f*1024 + lane*16 (zero bank conflicts by construction) and every staging
// write lands in a distinct 16B slot (also conflict-free). No padding, same math.
__global__ __launch_bounds__(256) void attn_mfma_kernel(const unsigned short* __restrict__ qn,
                                                        const unsigned short* __restrict__ kn,
                                                        const unsigned short* __restrict__ vn,
                                                        float* __restrict__ Opart,
                                                        float* __restrict__ Lpart) {
    __shared__ __align__(16) unsigned char Ksm[2][4096];
    __shared__ __align__(16) unsigned char Vsm[2][4096];
    int tid = threadIdx.x;
    int wq = tid >> 6, lane = tid & 63;
    int ln = lane & 15, quad = lane >> 4;
    int bid = blockIdx.x;
    int xcd = bid & 7, bi = bid >> 3;       // bi 0..287
    int nh = xcd * 2 + (bi >= 144);
    int bi2 = (bi >= 144) ? bi - 144 : bi;  // 0..143
    int qt = bi2 % 36, kz = bi2 / 36;       // kz 0..3
    const unsigned short* Qg = qn + (size_t)nh * 73728;
    const unsigned short* Kg = kn + (size_t)nh * 73728;
    const unsigned short* Vg = vn + (size_t)nh * 73728;

    bf16x8 qf = *(const bf16x8*)(Qg + (size_t)(qt * 64 + wq * 16 + ln) * 32 + quad * 8);
    bf16x8 ones;
#pragma unroll
    for (int i = 0; i < 8; ++i) ones[i] = (short)0x3F80;

    f32x4 o0 = {0.f, 0.f, 0.f, 0.f};
    f32x4 o1 = {0.f, 0.f, 0.f, 0.f};
    f32x4 lac = {0.f, 0.f, 0.f, 0.f};

    const int NT = 9;
    int s0 = kz * NT * 64;

    // fragment-major write offsets (tid-constant, all 256 slots distinct)
    int kr = tid >> 2, kg = tid & 3;                    // K: row, 16B-granule
    int koff = ((kr >> 4) << 10) | ((kg << 4) | (kr & 15)) << 4;
    int vd = tid >> 3, vg = tid & 7;                    // V: d-row, 16B-granule
    int voff = (((vg >> 2) * 2 + (vd >> 4)) << 10) | (((vg & 3) << 4) | (vd & 15)) << 4;
    int lb = lane << 4;                                 // read base = lane*16

    auto compute_tile = [&](int bsel) {
        const f32x4 zero = {0.f, 0.f, 0.f, 0.f};
        unsigned w[4][2];
#pragma unroll
        for (int c = 0; c < 4; ++c) {
            bf16x8 kf = *(const bf16x8*)(Ksm[bsel] + c * 1024 + lb);
            // swapped: lane holds S[q=ln][k=c*16+quad*4+r]
            f32x4 sc = __builtin_amdgcn_mfma_f32_16x16x32_bf16(kf, qf, zero, 0, 0, 0);
            w[c][0] = cvt_pk_bf16(exp2f(sc[0]), exp2f(sc[1]));
            w[c][1] = cvt_pk_bf16(exp2f(sc[2]), exp2f(sc[3]));
        }
#pragma unroll
        for (int kc = 0; kc < 2; ++kc) {
            unsigned a0 = w[2 * kc][0], b0 = w[2 * kc + 1][0];
            permlane32_swap(a0, b0);
            permlane16_swap(a0, b0);
            unsigned a1 = w[2 * kc][1], b1 = w[2 * kc + 1][1];
            permlane32_swap(a1, b1);
            permlane16_swap(a1, b1);
            union { unsigned u[4]; bf16x8 v8; } pk;
            pk.u[0] = a0; pk.u[1] = a1; pk.u[2] = b0; pk.u[3] = b1;
            bf16x8 v0 = *(const bf16x8*)(Vsm[bsel] + (kc * 2 + 0) * 1024 + lb);
            bf16x8 v1 = *(const bf16x8*)(Vsm[bsel] + (kc * 2 + 1) * 1024 + lb);
            lac = __builtin_amdgcn_mfma_f32_16x16x32_bf16(pk.v8, ones, lac, 0, 0, 0);
            o0  = __builtin_amdgcn_mfma_f32_16x16x32_bf16(pk.v8, v0, o0, 0, 0, 0);
            o1  = __builtin_amdgcn_mfma_f32_16x16x32_bf16(pk.v8, v1, o1, 0, 0, 0);
        }
    };

    // prologue: tile 0 -> LDS buf0; tile 1 -> regs B
    uint4 kA = *(const uint4*)(Kg + (size_t)s0 * 32 + tid * 8);
    uint4 vA = *(const uint4*)(Vg + (size_t)(tid >> 3) * SEQ + s0 + (tid & 7) * 8);
    *(uint4*)(Ksm[0] + koff) = kA;
    *(uint4*)(Vsm[0] + voff) = vA;
    uint4 kB = *(const uint4*)(Kg + (size_t)(s0 + 64) * 32 + tid * 8);
    uint4 vB = *(const uint4*)(Vg + (size_t)(tid >> 3) * SEQ + (s0 + 64) + (tid & 7) * 8);

    for (int i = 0; i < NT; i += 2) {
        if (i + 2 < NT) {
            int sn = s0 + (i + 2) * 64;
            kA = *(const uint4*)(Kg + (size_t)sn * 32 + tid * 8);
            vA = *(const uint4*)(Vg + (size_t)(tid >> 3) * SEQ + sn + (tid & 7) * 8);
        }
        __syncthreads();
        compute_tile(0);
        if (i + 1 < NT) {
            *(uint4*)(Ksm[1] + koff) = kB;
            *(uint4*)(Vsm[1] + voff) = vB;
        }
        if (i + 3 < NT) {
            int sn = s0 + (i + 3) * 64;
            kB = *(const uint4*)(Kg + (size_t)sn * 32 + tid * 8);
            vB = *(const uint4*)(Vg + (size_t)(tid >> 3) * SEQ + sn + (tid & 7) * 8);
        }
        __syncthreads();
        if (i + 1 < NT) compute_tile(1);
        if (i + 2 < NT) {
            *(uint4*)(Ksm[0] + koff) = kA;
            *(uint4*)(Vsm[0] + voff) = vA;
        }
    }

    // epilogue: write f32 partials (lac[r] is the row-sum for the same q-row as o0[r]/o1[r])
    float* Ob = Opart + ((size_t)(kz * 16 + nh) * 36 + qt) * 2048;
    float* Lb = Lpart + ((size_t)(kz * 16 + nh) * 36 + qt) * 64;
#pragma unroll
    for (int r = 0; r < 4; ++r) {
        int ql = wq * 16 + quad * 4 + r;
        Ob[ql * 32 + ln]      = o0[r];
        Ob[ql * 32 + 16 + ln] = o1[r];
        if (ln == 0) Lb[ql] = lac[r];
    }
}

// ---------------- Kernel 4: fused split-K reduce + out GEMM + residual (1152 blocks) ----------------
// UNCHANGED from R8 (verified passing).
__global__ __launch_bounds__(256) void out_gemm_kernel(const float* __restrict__ Opart,
                                                       const float* __restrict__ Lpart,
                                                       const unsigned short* __restrict__ wob,
                                                       const float* __restrict__ x,
                                                       float* __restrict__ out) {
    __shared__ float Linv[8][16];
    __shared__ __align__(16) unsigned short Ys[16][264];
    int bid = blockIdx.x;                  // 0..1151
    int xcd = bid & 7, j = bid >> 3;       // 0..143
    int mt = j & 3;
    int u = j >> 2;                        // 0..35
    int n = u & 1;
    int st = xcd * 18 + (u >> 1);          // 0..143 (16-s tiles)
    int qt = st >> 2;                      // 64-q tile
    int qo = (st & 3) * 16;                // offset within it
    int tid = threadIdx.x;

    // Phase A0: l sums
    if (tid < 128) {
        int h = tid >> 4, qi = tid & 15;
        size_t base = ((size_t)((n * 8 + h) * 36) + qt) * 64 + qo + qi;
        const size_t kzs = (size_t)16 * 36 * 64;
        float l = Lpart[base] + Lpart[base + kzs] + Lpart[base + 2 * kzs] + Lpart[base + 3 * kzs];
        Linv[h][qi] = 1.0f / l;
    }
    __syncthreads();
    // Phase A1: B-tile from Opart
    {
        int qi = tid >> 4, dp = tid & 15, d0 = dp * 2;
        const size_t kzs = (size_t)16 * 36 * 2048;
#pragma unroll
        for (int h = 0; h < 8; ++h) {
            size_t ob = ((size_t)((n * 8 + h) * 36) + qt) * 2048 + (size_t)(qo + qi) * 32 + d0;
            float2 a = *(const float2*)&Opart[ob];
            float2 b = *(const float2*)&Opart[ob + kzs];
            float2 e = *(const float2*)&Opart[ob + 2 * kzs];
            float2 f = *(const float2*)&Opart[ob + 3 * kzs];
            float li = Linv[h][qi];
            float r0 = ((a.x + b.x) + (e.x + f.x)) * li;
            float r1 = ((a.y + b.y) + (e.y + f.y)) * li;
            *(unsigned*)&Ys[qi][h * 32 + d0] = cvt_pk_bf16(r0, r1);
        }
    }
    __syncthreads();

    // Phase B: GEMM + residual
    int wave = tid >> 6, lane = tid & 63;
    int ln = lane & 15, quad = lane >> 4;
    int m0 = mt * 64 + wave * 16;
    const unsigned short* Abase = wob + (size_t)(m0 + ln) * 256 + quad * 8;
    f32x4 acc = (f32x4){0.f, 0.f, 0.f, 0.f};
#pragma unroll
    for (int kc = 0; kc < 8; ++kc) {
        bf16x8 a = *(const bf16x8*)(Abase + kc * 32);
        bf16x8 b = *(const bf16x8*)&Ys[ln][kc * 32 + quad * 8];
        acc = __builtin_amdgcn_mfma_f32_16x16x32_bf16(a, b, acc, 0, 0, 0);
    }
    const float c0f = 0.7f * 1.3130643285972254f;
    const float c1f = 0.3f * 1.3130643285972254f;
#pragma unroll
    for (int r = 0; r < 4; ++r) {
        int o = m0 + quad * 4 + r;
        int s = st * 16 + ln;
        size_t idx = (size_t)(n * 256 + o) * SEQ + s;
        out[idx] = c0f * x[idx] + c1f * acc[r];
    }
}

extern "C" void kernel_launch(void* const* d_in, const int* in_sizes, int n_in,
                              void* d_out, int out_size, void* d_ws, size_t ws_size,
                              hipStream_t stream) {
    (void)in_sizes; (void)n_in; (void)out_size; (void)ws_size;
    const float* x     = (const float*)d_in[0];
    const float* w_qkv = (const float*)d_in[1];
    const float* w_out = (const float*)d_in[2];
    float* out = (float*)d_out;
    float* ws  = (float*)d_ws;
    unsigned short* wqb = (unsigned short*)(ws);             // 98304 f
    unsigned short* wob = (unsigned short*)(ws + 98304);     // 32768 f
    unsigned short* qn  = (unsigned short*)(ws + 131072);    // 589824 f each
    unsigned short* kn  = (unsigned short*)(ws + 720896);
    unsigned short* vn  = (unsigned short*)(ws + 1310720);
    float* Opart = ws + 1900544;                             // 64*36*2048 = 4718592 f
    float* Lpart = ws + 6619136;                             // 64*36*64   =  147456 f

    hipLaunchKernelGGL(prep_w_kernel, dim3(256), dim3(256), 0, stream,
                       w_qkv, w_out, wqb, wob);
    hipLaunchKernelGGL(qkv_fused_kernel, dim3(1152), dim3(256), 0, stream,
                       x, wqb, qn, kn, vn);
    hipLaunchKernelGGL(attn_mfma_kernel, dim3(2304), dim3(256), 0, stream,
                       qn, kn, vn, Opart, Lpart);
    hipLaunchKernelGGL(out_gemm_kernel, dim3(1152), dim3(256), 0, stream,
                       Opart, Lpart, wob, x, out);
}

// Round 11
// 123.903 us; speedup vs baseline: 1.2220x; 1.0044x over previous
//
#include <hip/hip_runtime.h>
#include <math.h>

#define EPSN 1e-4f
#define SEQ 2304

using bf16x8 = __attribute__((ext_vector_type(8))) short;
using f32x4  = __attribute__((ext_vector_type(4))) float;

__device__ inline unsigned short f2bf(float x) {
    union { float f; unsigned u; } c; c.f = x;
    unsigned u = c.u;
    u += 0x7fffu + ((u >> 16) & 1u);
    return (unsigned short)(u >> 16);
}

// HW packed f32->bf16 (RNE), gfx950.
__device__ inline unsigned cvt_pk_bf16(float lo, float hi) {
    unsigned r;
    asm("v_cvt_pk_bf16_f32 %0, %1, %2" : "=v"(r) : "v"(lo), "v"(hi));
    return r;
}
// gfx950 cross-row swaps (verified passing R3-R10).
__device__ inline void permlane32_swap(unsigned &a, unsigned &b) {
    asm("v_permlane32_swap_b32 %0, %1" : "+v"(a), "+v"(b));
}
__device__ inline void permlane16_swap(unsigned &a, unsigned &b) {
    asm("v_permlane16_swap_b32 %0, %1" : "+v"(a), "+v"(b));
}

// ---------------- Kernel 1: weight-norm only (256 blocks) ----------------
__global__ __launch_bounds__(256) void prep_w_kernel(const float* __restrict__ w_qkv,
                                                     const float* __restrict__ w_out,
                                                     unsigned short* __restrict__ wqb,
                                                     unsigned short* __restrict__ wob) {
    int wave = threadIdx.x >> 6, lane = threadIdx.x & 63;
    int row = blockIdx.x * 4 + wave;
    const float* src;
    unsigned short* dst;
    if (row < 768) { src = w_qkv + (size_t)row * 256; dst = wqb + (size_t)row * 256; }
    else           { src = w_out + (size_t)(row - 768) * 256; dst = wob + (size_t)(row - 768) * 256; }
    float4 v = *(const float4*)&src[lane * 4];
    float ss = v.x * v.x + v.y * v.y + v.z * v.z + v.w * v.w;
    for (int off = 32; off > 0; off >>= 1) ss += __shfl_xor(ss, off, 64);
    float sc = 1.0f / (sqrtf(ss) + 16.0f * EPSN);
    unsigned p0 = (unsigned)f2bf(v.x * sc) | ((unsigned)f2bf(v.y * sc) << 16);
    unsigned p1 = (unsigned)f2bf(v.z * sc) | ((unsigned)f2bf(v.w * sc) << 16);
    *(uint2*)&dst[lane * 4] = make_uint2(p0, p1);
}

// ---------------- Kernel 2: fused x-transpose + QKV GEMM + d-normalize (1152 blocks) ----------------
// UNCHANGED from R8/R10 (verified passing).
__global__ __launch_bounds__(256) void qkv_fused_kernel(const float* __restrict__ x,
                                                        const unsigned short* __restrict__ wqb,
                                                        unsigned short* __restrict__ qn,
                                                        unsigned short* __restrict__ kn,
                                                        unsigned short* __restrict__ vn) {
    __shared__ __align__(16) unsigned short Xs[32][264];
    __shared__ float Cs[96][33];
    __shared__ __align__(16) unsigned short Vls[32][40];
    int bid = blockIdx.x;                   // 0..1151
    int xcd = bid & 7, j = bid >> 3;        // j 0..143
    int h = j & 7;
    int tile = xcd * 18 + (j >> 3);         // 0..143
    int st2 = tile % 72, n = tile / 72;     // 32-s tile, batch
    int tid = threadIdx.x;
    int wave = tid >> 6, lane = tid & 63;
    int ln = lane & 15, quad = lane >> 4;
    int sgrp = wave & 1, mgrp = wave >> 1;
    int s0 = st2 * 32;

    // stage x[n][c][s0..s0+31] -> Xs[s][c] bf16
    {
        int ci = tid >> 3, sv = (tid & 7) * 4;
#pragma unroll
        for (int p = 0; p < 8; ++p) {
            int c = p * 32 + ci;
            float4 v = *(const float4*)&x[(size_t)(n * 256 + c) * SEQ + s0 + sv];
            Xs[sv + 0][c] = f2bf(v.x);
            Xs[sv + 1][c] = f2bf(v.y);
            Xs[sv + 2][c] = f2bf(v.z);
            Xs[sv + 3][c] = f2bf(v.w);
        }
    }
    __syncthreads();

    const unsigned short* Abase = wqb + (size_t)(h * 96 + mgrp * 48 + ln) * 256 + quad * 8;
    f32x4 acc[3];
#pragma unroll
    for (int m = 0; m < 3; ++m) acc[m] = (f32x4){0.f, 0.f, 0.f, 0.f};
#pragma unroll
    for (int kc = 0; kc < 8; ++kc) {
        bf16x8 b = *(const bf16x8*)&Xs[sgrp * 16 + ln][kc * 32 + quad * 8];
#pragma unroll
        for (int m = 0; m < 3; ++m) {
            bf16x8 a = *(const bf16x8*)(Abase + (size_t)(m * 16) * 256 + kc * 32);
            acc[m] = __builtin_amdgcn_mfma_f32_16x16x32_bf16(a, b, acc[m], 0, 0, 0);
        }
    }
#pragma unroll
    for (int m = 0; m < 3; ++m)
#pragma unroll
        for (int r = 0; r < 4; ++r)
            Cs[mgrp * 48 + m * 16 + quad * 4 + r][sgrp * 16 + ln] = acc[m][r];
    __syncthreads();
    int nh = n * 8 + h;
    if (tid < 96) {
        int sl = tid & 31, wh = tid >> 5;
        int s = st2 * 32 + sl;
        float v[32];
        float ss = 0.f;
#pragma unroll
        for (int d = 0; d < 32; ++d) { v[d] = Cs[3 * d + wh][sl]; ss += v[d] * v[d]; }
        float inv = 1.0f / (EPSN + sqrtf(ss * (1.0f / 32.0f)));
        // fold softmax scale (1/sqrt(32)) AND log2(e) into q so attn uses exp2
        if (wh == 0) inv *= 0.17677669529663687f * 1.4426950408889634f;
        if (wh == 2) {
#pragma unroll
            for (int d = 0; d < 32; ++d) Vls[d][sl] = f2bf(v[d] * inv);
        } else {
            unsigned short* dst = (wh == 1 ? kn : qn) + (size_t)nh * 73728 + (size_t)s * 32;
            unsigned wbuf[16];
#pragma unroll
            for (int j2 = 0; j2 < 16; ++j2)
                wbuf[j2] = (unsigned)f2bf(v[2 * j2] * inv) | ((unsigned)f2bf(v[2 * j2 + 1] * inv) << 16);
#pragma unroll
            for (int j2 = 0; j2 < 4; ++j2) {
                uint4 t4 = make_uint4(wbuf[4 * j2], wbuf[4 * j2 + 1], wbuf[4 * j2 + 2], wbuf[4 * j2 + 3]);
                *(uint4*)(dst + j2 * 8) = t4;
            }
        }
    }
    __syncthreads();
    {
        int d = tid >> 3, sj = (tid & 7) * 4;
        uint2 t2 = *(const uint2*)&Vls[d][sj];
        *(uint2*)&vn[(size_t)nh * 73728 + (size_t)d * SEQ + st2 * 32 + sj] = t2;
    }
}

// ---------------- Kernel 3: MFMA flash attention, 8 waves / 2 q-tiles per block ----------------
// 512 thr = 2 q-halves x 4 q-subtiles sharing ONE K/V staging stream: waves 0-3 stage
// the K tile, waves 4-7 stage the V tile (one uint4 + one LDS write per thread per
// tile, wave-uniform). Fragment-major LDS (zero-conflict, from R10). Per-wave compute
// byte-identical to R10. Occupancy: 16KB LDS, ~48 VGPR -> 4 blocks x 8 waves = 32
// waves/CU (8/SIMD, up from ~3.5). Grid 1152 = 8 XCD x {2 heads x 18 qt128 x 4 kz}.
__global__ __launch_bounds__(512) void attn_mfma_kernel(const unsigned short* __restrict__ qn,
                                                        const unsigned short* __restrict__ kn,
                                                        const unsigned short* __restrict__ vn,
                                                        float* __restrict__ Opart,
                                                        float* __restrict__ Lpart) {
    __shared__ __align__(16) unsigned char Ksm[2][4096];
    __shared__ __align__(16) unsigned char Vsm[2][4096];
    int tid = threadIdx.x;
    int wave = tid >> 6, lane = tid & 63;
    int ln = lane & 15, quad = lane >> 4;
    int wq = wave & 3;                      // q-subtile within the 64-q half
    int bid = blockIdx.x;
    int xcd = bid & 7, bi = bid >> 3;       // bi 0..143
    int nh = xcd * 2 + (bi >= 72);
    int bi2 = (bi >= 72) ? bi - 72 : bi;    // 0..71
    int qt = bi2 % 18, kz = bi2 / 18;       // qt128 0..17, kz 0..3
    int qt64 = qt * 2 + (wave >> 2);        // this wave's 64-q tile (0..35)
    const unsigned short* Qg = qn + (size_t)nh * 73728;
    const unsigned short* Kg = kn + (size_t)nh * 73728;
    const unsigned short* Vg = vn + (size_t)nh * 73728;

    bf16x8 qf = *(const bf16x8*)(Qg + (size_t)(qt64 * 64 + wq * 16 + ln) * 32 + quad * 8);
    bf16x8 ones;
#pragma unroll
    for (int i = 0; i < 8; ++i) ones[i] = (short)0x3F80;

    f32x4 o0 = {0.f, 0.f, 0.f, 0.f};
    f32x4 o1 = {0.f, 0.f, 0.f, 0.f};
    f32x4 lac = {0.f, 0.f, 0.f, 0.f};

    const int NT = 9;
    int s0 = kz * NT * 64;

    // staging role: waves 0-3 stage K, waves 4-7 stage V (wave-uniform branch)
    int ts = tid & 255;
    bool isK = (tid < 256);
    // fragment-major write offset (from R10, applied to this thread's role)
    int kr = ts >> 2, kg = ts & 3;
    int koff = ((kr >> 4) << 10) | (((kg << 4) | (kr & 15)) << 4);
    int vd = ts >> 3, vg = ts & 7;
    int voff = (((vg >> 2) * 2 + (vd >> 4)) << 10) | ((((vg & 3) << 4) | (vd & 15)) << 4);
    int woff = isK ? koff : voff;
    int lb = lane << 4;                     // read base = lane*16

    auto gload = [&](int sn) -> uint4 {
        return isK ? *(const uint4*)(Kg + (size_t)sn * 32 + ts * 8)
                   : *(const uint4*)(Vg + (size_t)(ts >> 3) * SEQ + sn + (ts & 7) * 8);
    };
    auto swrite = [&](int buf, uint4 v) {
        *(uint4*)((isK ? Ksm[buf] : Vsm[buf]) + woff) = v;
    };

    auto compute_tile = [&](int bsel) {
        const f32x4 zero = {0.f, 0.f, 0.f, 0.f};
        unsigned w[4][2];
#pragma unroll
        for (int c = 0; c < 4; ++c) {
            bf16x8 kf = *(const bf16x8*)(Ksm[bsel] + c * 1024 + lb);
            // swapped: lane holds S[q=ln][k=c*16+quad*4+r]
            f32x4 sc = __builtin_amdgcn_mfma_f32_16x16x32_bf16(kf, qf, zero, 0, 0, 0);
            w[c][0] = cvt_pk_bf16(exp2f(sc[0]), exp2f(sc[1]));
            w[c][1] = cvt_pk_bf16(exp2f(sc[2]), exp2f(sc[3]));
        }
#pragma unroll
        for (int kc = 0; kc < 2; ++kc) {
            unsigned a0 = w[2 * kc][0], b0 = w[2 * kc + 1][0];
            permlane32_swap(a0, b0);
            permlane16_swap(a0, b0);
            unsigned a1 = w[2 * kc][1], b1 = w[2 * kc + 1][1];
            permlane32_swap(a1, b1);
            permlane16_swap(a1, b1);
            union { unsigned u[4]; bf16x8 v8; } pk;
            pk.u[0] = a0; pk.u[1] = a1; pk.u[2] = b0; pk.u[3] = b1;
            bf16x8 v0 = *(const bf16x8*)(Vsm[bsel] + (kc * 2 + 0) * 1024 + lb);
            bf16x8 v1 = *(const bf16x8*)(Vsm[bsel] + (kc * 2 + 1) * 1024 + lb);
            lac = __builtin_amdgcn_mfma_f32_16x16x32_bf16(pk.v8, ones, lac, 0, 0, 0);
            o0  = __builtin_amdgcn_mfma_f32_16x16x32_bf16(pk.v8, v0, o0, 0, 0, 0);
            o1  = __builtin_amdgcn_mfma_f32_16x16x32_bf16(pk.v8, v1, o1, 0, 0, 0);
        }
    };

    // prologue: tile 0 -> LDS buf0; tile 1 -> regs B
    uint4 rA = gload(s0);
    swrite(0, rA);
    uint4 rB = gload(s0 + 64);

    for (int i = 0; i < NT; i += 2) {
        if (i + 2 < NT) rA = gload(s0 + (i + 2) * 64);
        __syncthreads();
        compute_tile(0);
        if (i + 1 < NT) swrite(1, rB);
        if (i + 3 < NT) rB = gload(s0 + (i + 3) * 64);
        __syncthreads();
        if (i + 1 < NT) compute_tile(1);
        if (i + 2 < NT) swrite(0, rA);
    }

    // epilogue: write f32 partials (lac[r] is the row-sum for the same q-row as o0[r]/o1[r])
    float* Ob = Opart + ((size_t)(kz * 16 + nh) * 36 + qt64) * 2048;
    float* Lb = Lpart + ((size_t)(kz * 16 + nh) * 36 + qt64) * 64;
#pragma unroll
    for (int r = 0; r < 4; ++r) {
        int ql = wq * 16 + quad * 4 + r;
        Ob[ql * 32 + ln]      = o0[r];
        Ob[ql * 32 + 16 + ln] = o1[r];
        if (ln == 0) Lb[ql] = lac[r];
    }
}

// ---------------- Kernel 4: fused split-K reduce + out GEMM + residual (1152 blocks) ----------------
// UNCHANGED from R8/R10 (verified passing).
__global__ __launch_bounds__(256) void out_gemm_kernel(const float* __restrict__ Opart,
                                                       const float* __restrict__ Lpart,
                                                       const unsigned short* __restrict__ wob,
                                                       const float* __restrict__ x,
                                                       float* __restrict__ out) {
    __shared__ float Linv[8][16];
    __shared__ __align__(16) unsigned short Ys[16][264];
    int bid = blockIdx.x;                  // 0..1151
    int xcd = bid & 7, j = bid >> 3;       // 0..143
    int mt = j & 3;
    int u = j >> 2;                        // 0..35
    int n = u & 1;
    int st = xcd * 18 + (u >> 1);          // 0..143 (16-s tiles)
    int qt = st >> 2;                      // 64-q tile
    int qo = (st & 3) * 16;                // offset within it
    int tid = threadIdx.x;

    // Phase A0: l sums
    if (tid < 128) {
        int h = tid >> 4, qi = tid & 15;
        size_t base = ((size_t)((n * 8 + h) * 36) + qt) * 64 + qo + qi;
        const size_t kzs = (size_t)16 * 36 * 64;
        float l = Lpart[base] + Lpart[base + kzs] + Lpart[base + 2 * kzs] + Lpart[base + 3 * kzs];
        Linv[h][qi] = 1.0f / l;
    }
    __syncthreads();
    // Phase A1: B-tile from Opart
    {
        int qi = tid >> 4, dp = tid & 15, d0 = dp * 2;
        const size_t kzs = (size_t)16 * 36 * 2048;
#pragma unroll
        for (int h = 0; h < 8; ++h) {
            size_t ob = ((size_t)((n * 8 + h) * 36) + qt) * 2048 + (size_t)(qo + qi) * 32 + d0;
            float2 a = *(const float2*)&Opart[ob];
            float2 b = *(const float2*)&Opart[ob + kzs];
            float2 e = *(const float2*)&Opart[ob + 2 * kzs];
            float2 f = *(const float2*)&Opart[ob + 3 * kzs];
            float li = Linv[h][qi];
            float r0 = ((a.x + b.x) + (e.x + f.x)) * li;
            float r1 = ((a.y + b.y) + (e.y + f.y)) * li;
            *(unsigned*)&Ys[qi][h * 32 + d0] = cvt_pk_bf16(r0, r1);
        }
    }
    __syncthreads();

    // Phase B: GEMM + residual
    int wave = tid >> 6, lane = tid & 63;
    int ln = lane & 15, quad = lane >> 4;
    int m0 = mt * 64 + wave * 16;
    const unsigned short* Abase = wob + (size_t)(m0 + ln) * 256 + quad * 8;
    f32x4 acc = (f32x4){0.f, 0.f, 0.f, 0.f};
#pragma unroll
    for (int kc = 0; kc < 8; ++kc) {
        bf16x8 a = *(const bf16x8*)(Abase + kc * 32);
        bf16x8 b = *(const bf16x8*)&Ys[ln][kc * 32 + quad * 8];
        acc = __builtin_amdgcn_mfma_f32_16x16x32_bf16(a, b, acc, 0, 0, 0);
    }
    const float c0f = 0.7f * 1.3130643285972254f;
    const float c1f = 0.3f * 1.3130643285972254f;
#pragma unroll
    for (int r = 0; r < 4; ++r) {
        int o = m0 + quad * 4 + r;
        int s = st * 16 + ln;
        size_t idx = (size_t)(n * 256 + o) * SEQ + s;
        out[idx] = c0f * x[idx] + c1f * acc[r];
    }
}

extern "C" void kernel_launch(void* const* d_in, const int* in_sizes, int n_in,
                              void* d_out, int out_size, void* d_ws, size_t ws_size,
                              hipStream_t stream) {
    (void)in_sizes; (void)n_in; (void)out_size; (void)ws_size;
    const float* x     = (const float*)d_in[0];
    const float* w_qkv = (const float*)d_in[1];
    const float* w_out = (const float*)d_in[2];
    float* out = (float*)d_out;
    float* ws  = (float*)d_ws;
    unsigned short* wqb = (unsigned short*)(ws);             // 98304 f
    unsigned short* wob = (unsigned short*)(ws + 98304);     // 32768 f
    unsigned short* qn  = (unsigned short*)(ws + 131072);    // 589824 f each
    unsigned short* kn  = (unsigned short*)(ws + 720896);
    unsigned short* vn  = (unsigned short*)(ws + 1310720);
    float* Opart = ws + 1900544;                             // 64*36*2048 = 4718592 f
    float* Lpart = ws + 6619136;                             // 64*36*64   =  147456 f

    hipLaunchKernelGGL(prep_w_kernel, dim3(256), dim3(256), 0, stream,
                       w_qkv, w_out, wqb, wob);
    hipLaunchKernelGGL(qkv_fused_kernel, dim3(1152), dim3(256), 0, stream,
                       x, wqb, qn, kn, vn);
    hipLaunchKernelGGL(attn_mfma_kernel, dim3(1152), dim3(512), 0, stream,
                       qn, kn, vn, Opart, Lpart);
    hipLaunchKernelGGL(out_gemm_kernel, dim3(1152), dim3(256), 0, stream,
                       Opart, Lpart, wob, x, out);
}